// Round 3
// baseline (1798.621 us; speedup 1.0000x reference)
//
#include <hip/hip_runtime.h>
#include <cstdint>
#include <cmath>

#define N0   6144
#define FD   320
#define NN1  4915
#define NN2  2949
#define CAP  384

// ---------------- adjacency build: dense row -> compact column list ----------------
__global__ __launch_bounds__(256) void build_adj_k(const float* __restrict__ A,
                                                   int* __restrict__ adj, int* __restrict__ deg) {
  int w = blockIdx.x * 4 + (threadIdx.x >> 6);
  int lane = threadIdx.x & 63;
  if (w >= N0) return;
  const float* row = A + (size_t)w * N0;
  int* dst = adj + (size_t)w * CAP;
  int base = 0;
  unsigned long long lm = (1ull << lane) - 1ull;
  for (int j0 = 0; j0 < N0; j0 += 256) {
    float4 v = *(const float4*)(row + j0 + (lane << 2));
    bool f0 = v.x > 0.f, f1 = v.y > 0.f, f2 = v.z > 0.f, f3 = v.w > 0.f;
    unsigned long long m0 = __ballot(f0), m1 = __ballot(f1), m2 = __ballot(f2), m3 = __ballot(f3);
    int p = base + __popcll(m0 & lm) + __popcll(m1 & lm) + __popcll(m2 & lm) + __popcll(m3 & lm);
    int c0 = j0 + (lane << 2);
    if (f0) dst[p++] = c0;
    if (f1) dst[p++] = c0 + 1;
    if (f2) dst[p++] = c0 + 2;
    if (f3) dst[p++] = c0 + 3;
    base += __popcll(m0) + __popcll(m1) + __popcll(m2) + __popcll(m3);
  }
  if (lane == 0) deg[w] = base;
}

// subgraph adjacency: new row r <- old row idx[r], keep cols with inv[c]>=0, renumber
__global__ __launch_bounds__(256) void sub_adj_k(const int* __restrict__ adjs, const int* __restrict__ degs,
                                                 const int* __restrict__ idx, const int* __restrict__ inv,
                                                 int* __restrict__ adjd, int* __restrict__ degd, int k) {
  int w = blockIdx.x * 4 + (threadIdx.x >> 6);
  int lane = threadIdx.x & 63;
  if (w >= k) return;
  int o = idx[w];
  int d = degs[o];
  const int* src = adjs + (size_t)o * CAP;
  int* dst = adjd + (size_t)w * CAP;
  int base = 0;
  for (int t0 = 0; t0 < d; t0 += 64) {
    int tt = t0 + lane;
    int p = -1;
    if (tt < d) p = inv[src[tt]];
    unsigned long long m = __ballot(p >= 0);
    if (p >= 0) dst[base + __popcll(m & ((1ull << lane) - 1ull))] = p;
    base += (int)__popcll(m);
  }
  if (lane == 0) degd[w] = base;
}

// ================= tiled gather family =================
#define GATHER_CORE(XSRC)                                                        \
  int sub = lane & 15, g = lane >> 4;                                            \
  float4 a0 = {0,0,0,0}, a1 = {0,0,0,0}, a2 = {0,0,0,0}, a3 = {0,0,0,0}, a4 = {0,0,0,0}; \
  _Pragma("unroll 2")                                                            \
  for (int t = 0; t < d; t += 4) {                                               \
    int jj = lj[t + g];                                                          \
    float ww = lw[t + g];                                                        \
    const float* base = XSRC + (size_t)jj * FD + (sub << 2);                     \
    float4 v0 = *(const float4*)(base);                                          \
    float4 v1 = *(const float4*)(base + 64);                                     \
    float4 v2 = *(const float4*)(base + 128);                                    \
    float4 v3 = *(const float4*)(base + 192);                                    \
    float4 v4 = *(const float4*)(base + 256);                                    \
    a0.x = fmaf(ww, v0.x, a0.x); a0.y = fmaf(ww, v0.y, a0.y);                    \
    a0.z = fmaf(ww, v0.z, a0.z); a0.w = fmaf(ww, v0.w, a0.w);                    \
    a1.x = fmaf(ww, v1.x, a1.x); a1.y = fmaf(ww, v1.y, a1.y);                    \
    a1.z = fmaf(ww, v1.z, a1.z); a1.w = fmaf(ww, v1.w, a1.w);                    \
    a2.x = fmaf(ww, v2.x, a2.x); a2.y = fmaf(ww, v2.y, a2.y);                    \
    a2.z = fmaf(ww, v2.z, a2.z); a2.w = fmaf(ww, v2.w, a2.w);                    \
    a3.x = fmaf(ww, v3.x, a3.x); a3.y = fmaf(ww, v3.y, a3.y);                    \
    a3.z = fmaf(ww, v3.z, a3.z); a3.w = fmaf(ww, v3.w, a3.w);                    \
    a4.x = fmaf(ww, v4.x, a4.x); a4.y = fmaf(ww, v4.y, a4.y);                    \
    a4.z = fmaf(ww, v4.z, a4.z); a4.w = fmaf(ww, v4.w, a4.w);                    \
  }                                                                              \
  _Pragma("unroll")                                                              \
  for (int off = 16; off <= 32; off <<= 1) {                                     \
    a0.x += __shfl_xor(a0.x, off); a0.y += __shfl_xor(a0.y, off);                \
    a0.z += __shfl_xor(a0.z, off); a0.w += __shfl_xor(a0.w, off);                \
    a1.x += __shfl_xor(a1.x, off); a1.y += __shfl_xor(a1.y, off);                \
    a1.z += __shfl_xor(a1.z, off); a1.w += __shfl_xor(a1.w, off);                \
    a2.x += __shfl_xor(a2.x, off); a2.y += __shfl_xor(a2.y, off);                \
    a2.z += __shfl_xor(a2.z, off); a2.w += __shfl_xor(a2.w, off);                \
    a3.x += __shfl_xor(a3.x, off); a3.y += __shfl_xor(a3.y, off);                \
    a3.z += __shfl_xor(a3.z, off); a3.w += __shfl_xor(a3.w, off);                \
    a4.x += __shfl_xor(a4.x, off); a4.y += __shfl_xor(a4.y, off);                \
    a4.z += __shfl_xor(a4.z, off); a4.w += __shfl_xor(a4.w, off);                \
  }                                                                              \
  float4 osel = (g == 0) ? a0 : (g == 1) ? a1 : (g == 2) ? a2 : a3;

// Y[r,:] = sum_{j in N(r)} X[j,:]
__global__ __launch_bounds__(256) void spmm_k(const int* __restrict__ adj, const int* __restrict__ deg,
                                              const float* __restrict__ X, float* __restrict__ Y, int n) {
  __shared__ int ljs[4][CAP];
  __shared__ float lws[4][CAP];
  int wv = threadIdx.x >> 6, lane = threadIdx.x & 63;
  int w = blockIdx.x * 4 + wv;
  if (w >= n) return;
  int* lj = ljs[wv]; float* lw = lws[wv];
  int d = deg[w];
  const int* row = adj + (size_t)w * CAP;
  for (int t0 = 0; t0 < d; t0 += 64) {
    int tt = t0 + lane;
    lj[tt] = (tt < d) ? row[tt] : 0;
    lw[tt] = (tt < d) ? 1.0f : 0.0f;
  }
  GATHER_CORE(X)
  float* yr = Y + (size_t)w * FD;
  *(float4*)(yr + g * 64 + (sub << 2)) = osel;
  if (g == 0) *(float4*)(yr + 256 + (sub << 2)) = a4;
}

// fused level-1 down: builds subgraph adjacency row AND does the pool-gathered spmm.
__global__ __launch_bounds__(256) void down1_k(const int* __restrict__ adjs, const int* __restrict__ degs,
                                               const int* __restrict__ idx, const int* __restrict__ inv,
                                               const float* __restrict__ vals,
                                               const float* __restrict__ Xsrc,
                                               int* __restrict__ adjd, int* __restrict__ degd,
                                               float* __restrict__ Y, int n) {
  __shared__ int ljs[4][CAP];
  __shared__ float lws[4][CAP];
  int wv = threadIdx.x >> 6, lane = threadIdx.x & 63;
  int w = blockIdx.x * 4 + wv;
  if (w >= n) return;
  int* lj = ljs[wv]; float* lw = lws[wv];
  int o = idx[w];
  int d0 = degs[o];
  const int* src = adjs + (size_t)o * CAP;
  int* dst = adjd + (size_t)w * CAP;
  unsigned long long lm = (1ull << lane) - 1ull;
  int dc = 0;
  for (int t0 = 0; t0 < d0; t0 += 64) {
    int tt = t0 + lane;
    int j = (tt < d0) ? src[tt] : -1;
    int p = (j >= 0) ? inv[j] : -1;
    unsigned long long mk = __ballot(p >= 0);
    if (p >= 0) {
      int pos = dc + __popcll(mk & lm);
      dst[pos] = p;
      lj[pos] = j;
      lw[pos] = vals[p];
    }
    dc += (int)__popcll(mk);
  }
  if (lane < 4) { lj[dc + lane] = 0; lw[dc + lane] = 0.0f; }  // pad for t+g overhang
  if (lane == 0) degd[w] = dc;
  int d = dc;
  GATHER_CORE(Xsrc)
  float* yr = Y + (size_t)w * FD;
  *(float4*)(yr + g * 64 + (sub << 2)) = osel;
  if (g == 0) *(float4*)(yr + 256 + (sub << 2)) = a4;
}

// fused unpool + A@Xn with COMPACTED staging
__global__ __launch_bounds__(256) void mspmm_k(const int* __restrict__ adj, const int* __restrict__ deg,
                                               const int* __restrict__ inv,
                                               const float* __restrict__ Xp, float* __restrict__ Y, int n) {
  __shared__ int ljs[4][CAP];
  __shared__ float lws[4][CAP];
  int wv = threadIdx.x >> 6, lane = threadIdx.x & 63;
  int w = blockIdx.x * 4 + wv;
  if (w >= n) return;
  int* lj = ljs[wv]; float* lw = lws[wv];
  int d0 = deg[w];
  const int* row = adj + (size_t)w * CAP;
  unsigned long long lm = (1ull << lane) - 1ull;
  int dc = 0;
  for (int t0 = 0; t0 < d0; t0 += 64) {
    int tt = t0 + lane;
    int p = (tt < d0) ? inv[row[tt]] : -1;
    unsigned long long mk = __ballot(p >= 0);
    if (p >= 0) {
      int pos = dc + __popcll(mk & lm);
      lj[pos] = p;
      lw[pos] = 1.0f;
    }
    dc += (int)__popcll(mk);
  }
  if (lane < 4) { lj[dc + lane] = 0; lw[dc + lane] = 0.0f; }
  int d = dc;
  GATHER_CORE(Xp)
  float* yr = Y + (size_t)w * FD;
  *(float4*)(yr + g * 64 + (sub << 2)) = osel;
  if (g == 0) *(float4*)(yr + 256 + (sub << 2)) = a4;
}

// fused masked-softmax GAT row: out = elu( softmax_edges(LR(es_i+ed_j)) @ h )
__global__ __launch_bounds__(256) void gat_k(const int* __restrict__ adj, const int* __restrict__ deg,
                                             const float* __restrict__ h, const float* __restrict__ es,
                                             const float* __restrict__ ed, float* __restrict__ out, int n) {
  __shared__ int ljs[4][CAP];
  __shared__ float lws[4][CAP];
  int wv = threadIdx.x >> 6, lane = threadIdx.x & 63;
  int w = blockIdx.x * 4 + wv;
  if (w >= n) return;
  int* lj = ljs[wv]; float* lw = lws[wv];
  int d = deg[w];
  const int* row = adj + (size_t)w * CAP;
  float esr = es[w];
  float m = -INFINITY;
  for (int t0 = 0; t0 < d; t0 += 64) {
    int tt = t0 + lane;
    int j = (tt < d) ? row[tt] : 0;
    float e = -INFINITY;
    if (tt < d) {
      e = esr + ed[j];
      e = e >= 0.f ? e : 0.2f * e;
    }
    lj[tt] = j;
    lw[tt] = e;
    m = fmaxf(m, e);
  }
  #pragma unroll
  for (int off = 32; off; off >>= 1) m = fmaxf(m, __shfl_xor(m, off));
  float zacc = 0.f;
  for (int t0 = 0; t0 < d; t0 += 64) {
    int tt = t0 + lane;
    float wgt = expf(lw[tt] - m);
    lw[tt] = wgt;
    zacc += wgt;
  }
  #pragma unroll
  for (int off = 32; off; off >>= 1) zacc += __shfl_xor(zacc, off);
  GATHER_CORE(h)
  float* yr = out + (size_t)w * FD;
  float4 o;
  o.x = osel.x / zacc; o.y = osel.y / zacc; o.z = osel.z / zacc; o.w = osel.w / zacc;
  o.x = o.x > 0.f ? o.x : expm1f(o.x);
  o.y = o.y > 0.f ? o.y : expm1f(o.y);
  o.z = o.z > 0.f ? o.z : expm1f(o.z);
  o.w = o.w > 0.f ? o.w : expm1f(o.w);
  *(float4*)(yr + g * 64 + (sub << 2)) = o;
  if (g == 0) {
    float4 o4;
    o4.x = a4.x / zacc; o4.y = a4.y / zacc; o4.z = a4.z / zacc; o4.w = a4.w / zacc;
    o4.x = o4.x > 0.f ? o4.x : expm1f(o4.x);
    o4.y = o4.y > 0.f ? o4.y : expm1f(o4.y);
    o4.z = o4.z > 0.f ? o4.z : expm1f(o4.z);
    o4.w = o4.w > 0.f ? o4.w : expm1f(o4.w);
    *(float4*)(yr + 256 + (sub << 2)) = o4;
  }
}

// ---------------- bf16x3 split-precision MFMA GEMM ----------------
// C[n x 320] = A[n x K] @ W[K x 320] (+bias)(+add), optional A2 col-concat and
// rowidx/rowscale gather. x = h + m + l, each bf16 (8 mantissa bits); the three
// terms capture ~24 bits => exact-fp32-class split, NO overflow (bf16 range =
// fp32 range; fp16 overflowed at 65504 -> NaN in R2).
// A*B ~= a0b0 + (a0b1 + a1b0) + (a0b2 + a1b1 + a2b0); dropped terms ~2^-24 rel.
typedef __attribute__((ext_vector_type(8))) short bf16x8;
typedef __attribute__((ext_vector_type(4))) short s16x4;
typedef __attribute__((ext_vector_type(4))) float f32x4;

__device__ __forceinline__ short bf16rne(float x) {
  unsigned u = __float_as_uint(x);
  return (short)((u + 0x7fffu + ((u >> 16) & 1u)) >> 16);
}
__device__ __forceinline__ float bf16tof(short h) {
  return __uint_as_float(((unsigned)(unsigned short)h) << 16);
}

// weight preprocess: W [K][320] fp32 -> 3 bf16 splits, layout ((k/32)*320 + c)*32 + (k%32)
struct WPack {
  const float* src[7];
  short* sp[3][7];
  int K[7];
};
__global__ __launch_bounds__(256) void wprep_k(WPack p) {
  int mm = blockIdx.y;
  int K = p.K[mm];
  int total = K * FD;
  const float* src = p.src[mm];
  short* s0 = p.sp[0][mm];
  short* s1 = p.sp[1][mm];
  short* s2 = p.sp[2][mm];
  for (int i = blockIdx.x * 256 + threadIdx.x; i < total; i += gridDim.x * 256) {
    int k = i / FD, c = i - k * FD;
    float x = src[i];
    short h = bf16rne(x);
    float r = x - bf16tof(h);
    short m = bf16rne(r);
    short l = bf16rne(r - bf16tof(m));
    size_t o = ((size_t)((k >> 5) * FD + c) << 5) + (k & 31);
    s0[o] = h; s1[o] = m; s2[o] = l;
  }
}

// block: 32 rows x 160 cols, 4 waves (2 row x 2 col), wave tile 16x80 (5 frags).
// LDS rows padded to 40 halves (80 B) -> 16B-aligned frag reads, 2-way alias only.
__global__ __launch_bounds__(256) void mgemm_k(
    const float* __restrict__ A, const float* __restrict__ A2, int ksplit,
    const int* __restrict__ rowidx, const float* __restrict__ rowscale,
    const short* __restrict__ W0, const short* __restrict__ W1, const short* __restrict__ W2,
    const float* __restrict__ bias, const float* __restrict__ add,
    float* __restrict__ C, int n, int K) {
  __shared__ short Bs[3][160][40];
  __shared__ short As[3][32][40];
  int t = threadIdx.x;
  int lane = t & 63, wv = t >> 6;
  int wr = (wv >> 1) << 4;      // 0 / 16
  int wc = (wv & 1) * 80;       // 0 / 80
  int row0 = blockIdx.x << 5;
  int col0 = blockIdx.y * 160;
  int ar = t >> 3, ak = (t & 7) << 2;
  int grow = row0 + ar;
  int srow = grow; float sscale = 1.f;
  if (grow < n && rowidx) { srow = rowidx[grow]; sscale = rowscale[grow]; }
  auto load_a = [&](int k0) -> float4 {
    float4 av = make_float4(0.f, 0.f, 0.f, 0.f);
    if (grow < n) {
      int kk = k0 + ak;
      const float* src;
      if (A2 && kk >= ksplit) src = A2 + (size_t)srow * (K - ksplit) + (kk - ksplit);
      else                    src = A  + (size_t)srow * (A2 ? ksplit : K) + kk;
      av = *(const float4*)src;
      if (rowidx) { av.x *= sscale; av.y *= sscale; av.z *= sscale; av.w *= sscale; }
    }
    return av;
  };
  // W staging: per k-step 3 splits x 160 cols x 4 parts(8 halves) = 1920 16B chunks
  const short* wsrcp[8];
  short* wdstp[8];
  bool wact[8];
#pragma unroll
  for (int i = 0; i < 8; ++i) {
    int id = t + (i << 8);
    wact[i] = id < 1920;
    int iid = wact[i] ? id : 0;
    int s = iid / 640, rem = iid - s * 640;
    int c = rem >> 2, part = rem & 3;
    const short* wb = (s == 0) ? W0 : (s == 1) ? W1 : W2;
    wsrcp[i] = wb + (((size_t)(col0 + c)) << 5) + (part << 3);
    wdstp[i] = &Bs[s][c][part << 3];
  }
  auto load_w = [&](int ts, int4* regs) {
#pragma unroll
    for (int i = 0; i < 8; ++i)
      if (wact[i]) regs[i] = *(const int4*)(wsrcp[i] + (((size_t)ts * FD) << 5));
  };
  f32x4 acc0 = {0.f,0.f,0.f,0.f}, acc1 = acc0, acc2 = acc0, acc3 = acc0, acc4 = acc0;
  float4 av = load_a(0);
  int4 wreg[8];
  load_w(0, wreg);
  int fr = lane & 15, fq = lane >> 4;
  for (int ks = 0; ks < K; ks += 32) {
    {
      short h0 = bf16rne(av.x), h1 = bf16rne(av.y), h2 = bf16rne(av.z), h3 = bf16rne(av.w);
      float r0 = av.x - bf16tof(h0), r1 = av.y - bf16tof(h1),
            r2 = av.z - bf16tof(h2), r3 = av.w - bf16tof(h3);
      short m0 = bf16rne(r0), m1 = bf16rne(r1), m2 = bf16rne(r2), m3 = bf16rne(r3);
      s16x4 hv = {h0, h1, h2, h3};
      s16x4 mv = {m0, m1, m2, m3};
      s16x4 lv = {bf16rne(r0 - bf16tof(m0)), bf16rne(r1 - bf16tof(m1)),
                  bf16rne(r2 - bf16tof(m2)), bf16rne(r3 - bf16tof(m3))};
      *(s16x4*)&As[0][ar][ak] = hv;
      *(s16x4*)&As[1][ar][ak] = mv;
      *(s16x4*)&As[2][ar][ak] = lv;
#pragma unroll
      for (int i = 0; i < 8; ++i)
        if (wact[i]) *(int4*)wdstp[i] = wreg[i];
    }
    __syncthreads();
    if (ks + 32 < K) { av = load_a(ks + 32); load_w((ks >> 5) + 1, wreg); }
    bf16x8 a0 = *(const bf16x8*)&As[0][wr + fr][fq << 3];
    bf16x8 a1 = *(const bf16x8*)&As[1][wr + fr][fq << 3];
    bf16x8 a2 = *(const bf16x8*)&As[2][wr + fr][fq << 3];
#pragma unroll
    for (int c5 = 0; c5 < 5; ++c5) {
      bf16x8 b0 = *(const bf16x8*)&Bs[0][wc + (c5 << 4) + fr][fq << 3];
      bf16x8 b1 = *(const bf16x8*)&Bs[1][wc + (c5 << 4) + fr][fq << 3];
      bf16x8 b2 = *(const bf16x8*)&Bs[2][wc + (c5 << 4) + fr][fq << 3];
      f32x4& acc = (c5 == 0) ? acc0 : (c5 == 1) ? acc1 : (c5 == 2) ? acc2 : (c5 == 3) ? acc3 : acc4;
      acc = __builtin_amdgcn_mfma_f32_16x16x32_bf16(a2, b0, acc, 0, 0, 0);
      acc = __builtin_amdgcn_mfma_f32_16x16x32_bf16(a1, b1, acc, 0, 0, 0);
      acc = __builtin_amdgcn_mfma_f32_16x16x32_bf16(a0, b2, acc, 0, 0, 0);
      acc = __builtin_amdgcn_mfma_f32_16x16x32_bf16(a1, b0, acc, 0, 0, 0);
      acc = __builtin_amdgcn_mfma_f32_16x16x32_bf16(a0, b1, acc, 0, 0, 0);
      acc = __builtin_amdgcn_mfma_f32_16x16x32_bf16(a0, b0, acc, 0, 0, 0);
    }
    __syncthreads();
  }
  // epilogue: C/D frag mapping col=lane&15, row=(lane>>4)*4+reg (m89-verified)
#pragma unroll
  for (int c5 = 0; c5 < 5; ++c5) {
    f32x4 acc = (c5 == 0) ? acc0 : (c5 == 1) ? acc1 : (c5 == 2) ? acc2 : (c5 == 3) ? acc3 : acc4;
    int c = col0 + wc + (c5 << 4) + fr;
#pragma unroll
    for (int i = 0; i < 4; ++i) {
      int r = row0 + wr + (fq << 2) + i;
      if (r < n) {
        float v = acc[i];
        if (bias) v += bias[c];
        if (add)  v += add[(size_t)r * FD + c];
        C[(size_t)r * FD + c] = v;
      }
    }
  }
}

static inline unsigned cdiv(int a, int b) { return (unsigned)((a + b - 1) / b); }

static void launch_mgemm(const float* A, short* const* Wsp,
                         const float* bias, const float* add,
                         float* C, int n, int K, hipStream_t stream, const float* A2 = nullptr,
                         int ksplit = 0, const int* rowidx = nullptr, const float* rowscale = nullptr) {
  mgemm_k<<<dim3(cdiv(n, 32), 2), dim3(256), 0, stream>>>(A, A2, ksplit, rowidx, rowscale,
                                                          Wsp[0], Wsp[1], Wsp[2], bias, add, C, n, K);
}

// ---------------- GAT helpers ----------------
__global__ __launch_bounds__(256) void esed_k(const float* __restrict__ h, const float* __restrict__ a,
                                              float* __restrict__ es, float* __restrict__ ed, int n) {
  int w = blockIdx.x * 4 + (threadIdx.x >> 6);
  int lane = threadIdx.x & 63;
  if (w >= n) return;
  const float* hr = h + (size_t)w * FD;
  const float* a2 = a + FD;
  float sa = 0.f, sb = 0.f;
#pragma unroll
  for (int c = 0; c < 5; ++c) {
    float hv = hr[lane + 64 * c];
    sa += hv * a[lane + 64 * c];
    sb += hv * a2[lane + 64 * c];
  }
  for (int o = 32; o; o >>= 1) { sa += __shfl_xor(sa, o); sb += __shfl_xor(sb, o); }
  if (lane == 0) { es[w] = sa; ed[w] = sb; }
}

// ---------------- pooling: fused score + key build + rank zero ----------------
__global__ __launch_bounds__(256) void scorekey_k(const float* __restrict__ X, const float* __restrict__ pw,
                                                  const float* __restrict__ pb,
                                                  unsigned long long* __restrict__ keys,
                                                  int* __restrict__ rank, int n) {
  int w = blockIdx.x * 4 + (threadIdx.x >> 6);
  int lane = threadIdx.x & 63;
  if (w >= n) return;
  const float* xr = X + (size_t)w * FD;
  float s = 0.f;
#pragma unroll
  for (int c = 0; c < 5; ++c) s += xr[lane + 64 * c] * pw[lane + 64 * c];
  for (int o = 32; o; o >>= 1) s += __shfl_xor(s, o);
  if (lane == 0) {
    float u = (s + pb[0]) / 100.0f;
    float sc = 1.0f / (1.0f + expf(-u));
    keys[w] = ((unsigned long long)__float_as_uint(sc) << 32) | (unsigned int)(~w);
    rank[w] = 0;
  }
}

#define RANK_TILE 1024
__global__ __launch_bounds__(256) void rank_count_k(const unsigned long long* __restrict__ keys,
                                                    int n, int jchunk, int* __restrict__ rank) {
  __shared__ unsigned long long tile[RANK_TILE];
  int i = blockIdx.x * 256 + threadIdx.x;
  unsigned long long my = (i < n) ? keys[i] : 0ull;
  int j0 = blockIdx.y * jchunk;
  int jend = j0 + jchunk; if (jend > n) jend = n;
  int cnt = 0;
  for (int t0 = j0; t0 < jend; t0 += RANK_TILE) {
    int m = jend - t0; if (m > RANK_TILE) m = RANK_TILE;
    for (int t = threadIdx.x; t < m; t += 256) tile[t] = keys[t0 + t];
    __syncthreads();
    for (int t = 0; t < m; ++t) cnt += (tile[t] > my) ? 1 : 0;
    __syncthreads();
  }
  if (i < n && cnt) atomicAdd(&rank[i], cnt);
}

__global__ __launch_bounds__(256) void rank_scatter_k(const unsigned long long* __restrict__ keys,
                                                      const int* __restrict__ rank, int n, int k,
                                                      int* __restrict__ idx_out, float* __restrict__ vals_out,
                                                      int* __restrict__ inv) {
  int i = blockIdx.x * 256 + threadIdx.x;
  if (i >= n) return;
  int r = rank[i];
  inv[i] = (r < k) ? r : -1;
  if (r < k) {
    idx_out[r] = i;
    vals_out[r] = __uint_as_float((unsigned int)(keys[i] >> 32));
  }
}

// ---------------- host ----------------
static inline dim3 wgrid(int n) { return dim3((unsigned)((n + 3) / 4)); }

struct TopkBufs { unsigned long long* keys; int* rank; };

static void launch_topk(int n, int k, int* idx_out, float* vals_out, int* inv,
                        TopkBufs tb, hipStream_t stream) {
  const int JS = 8;
  int jchunk = (n + JS - 1) / JS;
  rank_count_k<<<dim3(cdiv(n, 256), JS), dim3(256), 0, stream>>>(tb.keys, n, jchunk, tb.rank);
  rank_scatter_k<<<cdiv(n, 256), dim3(256), 0, stream>>>(tb.keys, tb.rank, n, k, idx_out, vals_out, inv);
}

extern "C" void kernel_launch(void* const* d_in, const int* in_sizes, int n_in,
                              void* d_out, int out_size, void* d_ws, size_t ws_size,
                              hipStream_t stream) {
  const float* A      = (const float*)d_in[0];
  const float* X0     = (const float*)d_in[1];
  const float* sg_W   = (const float*)d_in[2];
  const float* sg_a   = (const float*)d_in[3];
  const float* bg_W   = (const float*)d_in[4];
  const float* bg_a   = (const float*)d_in[5];
  const float* eg_W   = (const float*)d_in[6];
  const float* eg_a   = (const float*)d_in[7];
  const float* down_W = (const float*)d_in[8];
  const float* down_b = (const float*)d_in[9];
  const float* up_W   = (const float*)d_in[10];
  const float* up_b   = (const float*)d_in[11];
  const float* pool_w = (const float*)d_in[12];
  const float* pool_b = (const float*)d_in[13];
  float* out = (float*)d_out;
  char* ws = (char*)d_ws;

  size_t off = 0;
  auto alloc = [&](size_t bytes) -> char* {
    char* p = ws + off;
    off += (bytes + 255) & ~(size_t)255;
    return p;
  };
  int* adj0  = (int*)alloc((size_t)N0 * CAP * 4);
  int* deg0  = (int*)alloc((size_t)N0 * 4);
  int* adj1a = (int*)alloc((size_t)NN1 * CAP * 4);
  int* deg1a = (int*)alloc((size_t)NN1 * 4);
  int* adj1b = (int*)alloc((size_t)NN1 * CAP * 4);
  int* deg1b = (int*)alloc((size_t)NN1 * 4);
  int* adj2  = (int*)alloc((size_t)NN2 * CAP * 4);
  int* deg2  = (int*)alloc((size_t)NN2 * 4);
  int* inv0a = (int*)alloc((size_t)N0 * 4);
  int* inv0b = (int*)alloc((size_t)N0 * 4);
  int* inv1a = (int*)alloc((size_t)NN1 * 4);
  int* inv1b = (int*)alloc((size_t)NN1 * 4);
  int* idx0a = (int*)alloc((size_t)NN1 * 4);
  int* idx0b = (int*)alloc((size_t)NN1 * 4);
  int* idx1a = (int*)alloc((size_t)NN2 * 4);
  int* idx1b = (int*)alloc((size_t)NN2 * 4);
  unsigned long long* keys = (unsigned long long*)alloc((size_t)N0 * 8);
  int* rankb = (int*)alloc((size_t)N0 * 4);
  float* vals   = (float*)alloc((size_t)N0 * 4);
  float* es     = (float*)alloc((size_t)N0 * 4);
  float* ed     = (float*)alloc((size_t)N0 * 4);
  float* hbuf   = (float*)alloc((size_t)N0 * FD * 4);
  float* S      = (float*)alloc((size_t)N0 * FD * 4);
  float* Xcur   = (float*)alloc((size_t)N0 * FD * 4);
  float* d0a    = (float*)alloc((size_t)N0 * FD * 4);
  float* d1a    = (float*)alloc((size_t)NN1 * FD * 4);
  float* d0b    = (float*)alloc((size_t)N0 * FD * 4);
  float* d1b    = (float*)alloc((size_t)NN1 * FD * 4);
  float* Xb     = (float*)alloc((size_t)NN2 * FD * 4);
  float* Xu1    = (float*)alloc((size_t)NN1 * FD * 4);
  float* Xu0    = (float*)alloc((size_t)N0 * FD * 4);

  // bf16x3 weight splits: [sg, down0, down1, up0, up1, bg, eg]
  const int   Ks[7]   = {FD, FD, FD, FD, FD, FD, 2 * FD};
  const float* wsrc[7] = {sg_W, down_W, down_W + FD * FD, up_W, up_W + FD * FD, bg_W, eg_W};
  short* wsp[7][3];
  for (int i = 0; i < 7; ++i)
    for (int s = 0; s < 3; ++s)
      wsp[i][s] = (short*)alloc((size_t)Ks[i] * FD * 2);

  TopkBufs tb{keys, rankb};
  dim3 b256(256);

  WPack pk;
  for (int i = 0; i < 7; ++i) {
    pk.src[i] = wsrc[i]; pk.K[i] = Ks[i];
    for (int s = 0; s < 3; ++s) pk.sp[s][i] = wsp[i][s];
  }
  wprep_k<<<dim3(400, 7), b256, 0, stream>>>(pk);

  build_adj_k<<<wgrid(N0), b256, 0, stream>>>(A, adj0, deg0);

  float* orgX = out + (size_t)N0 * FD;   // "start" output, also org_X
  launch_mgemm(X0, wsp[0], nullptr, nullptr, hbuf, N0, FD, stream);
  esed_k<<<wgrid(N0), b256, 0, stream>>>(hbuf, sg_a, es, ed, N0);
  gat_k<<<wgrid(N0), b256, 0, stream>>>(adj0, deg0, hbuf, es, ed, orgX, N0);

  const float* Xin = orgX;
  for (int pass = 0; pass < 2; ++pass) {
    int* idx0p = pass ? idx0b : idx0a;
    int* inv0p = pass ? inv0b : inv0a;
    int* idx1p = pass ? idx1b : idx1a;
    int* inv1p = pass ? inv1b : inv1a;
    int* adj1p = pass ? adj1b : adj1a;
    int* deg1p = pass ? deg1b : deg1a;
    float* d0p = pass ? d0b : d0a;
    float* d1p = pass ? d1b : d1a;

    // ---- down level 0 (n = N0) ----
    spmm_k<<<wgrid(N0), b256, 0, stream>>>(adj0, deg0, Xin, S, N0);
    launch_mgemm(S, wsp[1], down_b, nullptr, d0p, N0, FD, stream);
    scorekey_k<<<wgrid(N0), b256, 0, stream>>>(d0p, pool_w, pool_b, keys, rankb, N0);
    launch_topk(N0, NN1, idx0p, vals, inv0p, tb, stream);

    // ---- down level 1 (n = NN1): sub_adj + pool-gather spmm fused ----
    down1_k<<<wgrid(NN1), b256, 0, stream>>>(adj0, deg0, idx0p, inv0p, vals, d0p,
                                             adj1p, deg1p, S, NN1);
    launch_mgemm(S, wsp[2], down_b + FD, nullptr, d1p, NN1, FD, stream);
    scorekey_k<<<wgrid(NN1), b256, 0, stream>>>(d1p, pool_w + FD, pool_b + 1, keys, rankb, NN1);
    launch_topk(NN1, NN2, idx1p, vals, inv1p, tb, stream);
    sub_adj_k<<<wgrid(NN2), b256, 0, stream>>>(adj1p, deg1p, idx1p, inv1p, adj2, deg2, NN2);

    // ---- bottom GAT (n = NN2): pool-gather fused into the GEMM A-loader ----
    launch_mgemm(d1p, wsp[5], nullptr, nullptr, hbuf, NN2, FD, stream, nullptr, 0, idx1p, vals);
    esed_k<<<wgrid(NN2), b256, 0, stream>>>(hbuf, bg_a, es, ed, NN2);
    gat_k<<<wgrid(NN2), b256, 0, stream>>>(adj2, deg2, hbuf, es, ed, Xb, NN2);

    // ---- up path: ALWAYS pass-1 ("a") graph state, per reference indexing ----
    mspmm_k<<<wgrid(NN1), b256, 0, stream>>>(adj1a, deg1a, inv1a, Xb, S, NN1);
    launch_mgemm(S, wsp[3], up_b, d1a, Xu1, NN1, FD, stream);
    mspmm_k<<<wgrid(N0), b256, 0, stream>>>(adj0, deg0, inv0a, Xu1, S, N0);
    launch_mgemm(S, wsp[4], up_b + FD, d0a, Xu0, N0, FD, stream);

    // ---- end GAT on concat([Xu0, org_X]) fused into the GEMM A-loader ----
    launch_mgemm(Xu0, wsp[6], nullptr, nullptr, hbuf, N0, 2 * FD, stream, orgX, FD);
    esed_k<<<wgrid(N0), b256, 0, stream>>>(hbuf, eg_a, es, ed, N0);
    float* egout = pass ? out : Xcur;
    gat_k<<<wgrid(N0), b256, 0, stream>>>(adj0, deg0, hbuf, es, ed, egout, N0);
    Xin = egout;
  }
}

// Round 4
// 1476.708 us; speedup vs baseline: 1.2180x; 1.2180x over previous
//
#include <hip/hip_runtime.h>
#include <cstdint>
#include <cmath>

#define N0   6144
#define FD   320
#define NN1  4915
#define NN2  2949
#define CAP  384

typedef float f32x4g __attribute__((ext_vector_type(4)));
__device__ __forceinline__ void ntst4(float* p, float4 v) {
  f32x4g t; t.x = v.x; t.y = v.y; t.z = v.z; t.w = v.w;
  __builtin_nontemporal_store(t, (f32x4g*)p);
}

// ---------------- adjacency build: dense row -> compact column list ----------------
__global__ __launch_bounds__(256) void build_adj_k(const float* __restrict__ A,
                                                   int* __restrict__ adj, int* __restrict__ deg) {
  int w = blockIdx.x * 4 + (threadIdx.x >> 6);
  int lane = threadIdx.x & 63;
  if (w >= N0) return;
  const float* row = A + (size_t)w * N0;
  int* dst = adj + (size_t)w * CAP;
  int base = 0;
  unsigned long long lm = (1ull << lane) - 1ull;
  for (int j0 = 0; j0 < N0; j0 += 256) {
    float4 v = *(const float4*)(row + j0 + (lane << 2));
    bool f0 = v.x > 0.f, f1 = v.y > 0.f, f2 = v.z > 0.f, f3 = v.w > 0.f;
    unsigned long long m0 = __ballot(f0), m1 = __ballot(f1), m2 = __ballot(f2), m3 = __ballot(f3);
    int p = base + __popcll(m0 & lm) + __popcll(m1 & lm) + __popcll(m2 & lm) + __popcll(m3 & lm);
    int c0 = j0 + (lane << 2);
    if (f0) dst[p++] = c0;
    if (f1) dst[p++] = c0 + 1;
    if (f2) dst[p++] = c0 + 2;
    if (f3) dst[p++] = c0 + 3;
    base += __popcll(m0) + __popcll(m1) + __popcll(m2) + __popcll(m3);
  }
  if (lane == 0) deg[w] = base;
}

// subgraph adjacency: new row r <- old row idx[r], keep cols with inv[c]>=0, renumber
__global__ __launch_bounds__(256) void sub_adj_k(const int* __restrict__ adjs, const int* __restrict__ degs,
                                                 const int* __restrict__ idx, const int* __restrict__ inv,
                                                 int* __restrict__ adjd, int* __restrict__ degd, int k) {
  int w = blockIdx.x * 4 + (threadIdx.x >> 6);
  int lane = threadIdx.x & 63;
  if (w >= k) return;
  int o = idx[w];
  int d = degs[o];
  const int* src = adjs + (size_t)o * CAP;
  int* dst = adjd + (size_t)w * CAP;
  int base = 0;
  for (int t0 = 0; t0 < d; t0 += 64) {
    int tt = t0 + lane;
    int p = -1;
    if (tt < d) p = inv[src[tt]];
    unsigned long long m = __ballot(p >= 0);
    if (p >= 0) dst[base + __popcll(m & ((1ull << lane) - 1ull))] = p;
    base += (int)__popcll(m);
  }
  if (lane == 0) degd[w] = base;
}

// ================= tiled gather family =================
// One wave per row; (idx,weight) staged in LDS; 4 neighbors in flight
// (g = lane>>4), sub = lane&15 covers float4 slices of chunks [C0, C0+NC)
// (chunk = 64 floats); xor-reduce over groups {16,32}; group g stores
// chunks c with (c&3)==g.
// N0-sourced sites are column-split into 3 serialized launches
// (128/128/64 cols -> X-slice 3.1/3.1/1.6 MB, L2-resident per XCD);
// adjacency/weight streams use nontemporal loads and outputs nontemporal
// stores so only the X-chunk occupies L2.
#define GATHER_CORE(XSRC)                                                        \
  int sub = lane & 15, g = lane >> 4;                                            \
  float4 acc[NC];                                                                \
  _Pragma("unroll") for (int c = 0; c < NC; ++c) acc[c] = make_float4(0.f,0.f,0.f,0.f); \
  _Pragma("unroll 2")                                                            \
  for (int t = 0; t < d; t += 4) {                                               \
    int jj = lj[t + g];                                                          \
    float ww = lw[t + g];                                                        \
    const float* base = XSRC + (size_t)jj * FD + (C0 * 64) + (sub << 2);         \
    float4 v[NC];                                                                \
    _Pragma("unroll") for (int c = 0; c < NC; ++c) v[c] = *(const float4*)(base + 64 * c); \
    _Pragma("unroll") for (int c = 0; c < NC; ++c) {                             \
      acc[c].x = fmaf(ww, v[c].x, acc[c].x);                                     \
      acc[c].y = fmaf(ww, v[c].y, acc[c].y);                                     \
      acc[c].z = fmaf(ww, v[c].z, acc[c].z);                                     \
      acc[c].w = fmaf(ww, v[c].w, acc[c].w); }                                   \
  }                                                                              \
  _Pragma("unroll")                                                              \
  for (int off = 16; off <= 32; off <<= 1) {                                     \
    _Pragma("unroll") for (int c = 0; c < NC; ++c) {                             \
      acc[c].x += __shfl_xor(acc[c].x, off);                                     \
      acc[c].y += __shfl_xor(acc[c].y, off);                                     \
      acc[c].z += __shfl_xor(acc[c].z, off);                                     \
      acc[c].w += __shfl_xor(acc[c].w, off); }                                   \
  }

// pure weighted gather over a column chunk. Sources for (idx,weight):
//   ljg ? compacted global list (+dcomp degree) : adj/deg (weight = lwg or 1.0)
// ZS: divide by zbuf[w] + elu (GAT epilogue chunks).
template<int C0, int NC, bool ZS>
__global__ __launch_bounds__(256) void gatherw_k(const int* __restrict__ adj, const int* __restrict__ deg,
                                                 const int* __restrict__ ljg, const float* __restrict__ lwg,
                                                 const int* __restrict__ dcomp,
                                                 const float* __restrict__ X, const float* __restrict__ zbuf,
                                                 float* __restrict__ Y, int n) {
  __shared__ int ljs[4][CAP];
  __shared__ float lws[4][CAP];
  int wv = threadIdx.x >> 6, lane = threadIdx.x & 63;
  int w = blockIdx.x * 4 + wv;
  if (w >= n) return;
  int* lj = ljs[wv]; float* lw = lws[wv];
  int d = dcomp ? dcomp[w] : deg[w];
  const int* jsrc = (ljg ? ljg : adj) + (size_t)w * CAP;
  const float* wsrc = lwg ? lwg + (size_t)w * CAP : nullptr;
  for (int t0 = 0; t0 < d; t0 += 64) {
    int tt = t0 + lane;
    lj[tt] = (tt < d) ? __builtin_nontemporal_load(jsrc + tt) : 0;
    lw[tt] = (tt < d) ? (wsrc ? __builtin_nontemporal_load(wsrc + tt) : 1.0f) : 0.0f;
  }
  GATHER_CORE(X)
  float* yr = Y + (size_t)w * FD + (C0 * 64);
  float z = ZS ? zbuf[w] : 1.0f;
  #pragma unroll
  for (int c = 0; c < NC; ++c)
    if ((c & 3) == g) {
      float4 o = acc[c];
      if (ZS) {
        o.x = o.x / z; o.y = o.y / z; o.z = o.z / z; o.w = o.w / z;
        o.x = o.x > 0.f ? o.x : expm1f(o.x);
        o.y = o.y > 0.f ? o.y : expm1f(o.y);
        o.z = o.z > 0.f ? o.z : expm1f(o.z);
        o.w = o.w > 0.f ? o.w : expm1f(o.w);
      }
      ntst4(yr + c * 64 + (sub << 2), o);
    }
}

// GAT chunk-0: full softmax prep (weights stored to wexp, z to zbuf) + gather cols 0..127
__global__ __launch_bounds__(256) void gat0_k(const int* __restrict__ adj, const int* __restrict__ deg,
                                              const float* __restrict__ h, const float* __restrict__ es,
                                              const float* __restrict__ ed,
                                              float* __restrict__ wexp, float* __restrict__ zbuf,
                                              float* __restrict__ out, int n) {
  constexpr int C0 = 0, NC = 2;
  __shared__ int ljs[4][CAP];
  __shared__ float lws[4][CAP];
  int wv = threadIdx.x >> 6, lane = threadIdx.x & 63;
  int w = blockIdx.x * 4 + wv;
  if (w >= n) return;
  int* lj = ljs[wv]; float* lw = lws[wv];
  int d = deg[w];
  const int* row = adj + (size_t)w * CAP;
  float esr = es[w];
  float m = -INFINITY;
  for (int t0 = 0; t0 < d; t0 += 64) {
    int tt = t0 + lane;
    int j = (tt < d) ? __builtin_nontemporal_load(row + tt) : 0;
    float e = -INFINITY;
    if (tt < d) {
      e = esr + ed[j];
      e = e >= 0.f ? e : 0.2f * e;
    }
    lj[tt] = j;
    lw[tt] = e;
    m = fmaxf(m, e);
  }
  #pragma unroll
  for (int off = 32; off; off >>= 1) m = fmaxf(m, __shfl_xor(m, off));
  float zacc = 0.f;
  float* we = wexp + (size_t)w * CAP;
  for (int t0 = 0; t0 < d; t0 += 64) {
    int tt = t0 + lane;
    float wgt = expf(lw[tt] - m);
    lw[tt] = wgt;
    __builtin_nontemporal_store(wgt, we + tt);
    zacc += wgt;
  }
  #pragma unroll
  for (int off = 32; off; off >>= 1) zacc += __shfl_xor(zacc, off);
  if (lane == 0) zbuf[w] = zacc;
  GATHER_CORE(h)
  float* yr = out + (size_t)w * FD;
  #pragma unroll
  for (int c = 0; c < NC; ++c)
    if ((c & 3) == g) {
      float4 o = acc[c];
      o.x = o.x / zacc; o.y = o.y / zacc; o.z = o.z / zacc; o.w = o.w / zacc;
      o.x = o.x > 0.f ? o.x : expm1f(o.x);
      o.y = o.y > 0.f ? o.y : expm1f(o.y);
      o.z = o.z > 0.f ? o.z : expm1f(o.z);
      o.w = o.w > 0.f ? o.w : expm1f(o.w);
      ntst4(yr + c * 64 + (sub << 2), o);
    }
}

// full fused GAT (single launch) for NN2-sized graphs (source L2-fits)
__global__ __launch_bounds__(256) void gat_k(const int* __restrict__ adj, const int* __restrict__ deg,
                                             const float* __restrict__ h, const float* __restrict__ es,
                                             const float* __restrict__ ed, float* __restrict__ out, int n) {
  constexpr int C0 = 0, NC = 5;
  __shared__ int ljs[4][CAP];
  __shared__ float lws[4][CAP];
  int wv = threadIdx.x >> 6, lane = threadIdx.x & 63;
  int w = blockIdx.x * 4 + wv;
  if (w >= n) return;
  int* lj = ljs[wv]; float* lw = lws[wv];
  int d = deg[w];
  const int* row = adj + (size_t)w * CAP;
  float esr = es[w];
  float m = -INFINITY;
  for (int t0 = 0; t0 < d; t0 += 64) {
    int tt = t0 + lane;
    int j = (tt < d) ? __builtin_nontemporal_load(row + tt) : 0;
    float e = -INFINITY;
    if (tt < d) {
      e = esr + ed[j];
      e = e >= 0.f ? e : 0.2f * e;
    }
    lj[tt] = j;
    lw[tt] = e;
    m = fmaxf(m, e);
  }
  #pragma unroll
  for (int off = 32; off; off >>= 1) m = fmaxf(m, __shfl_xor(m, off));
  float zacc = 0.f;
  for (int t0 = 0; t0 < d; t0 += 64) {
    int tt = t0 + lane;
    float wgt = expf(lw[tt] - m);
    lw[tt] = wgt;
    zacc += wgt;
  }
  #pragma unroll
  for (int off = 32; off; off >>= 1) zacc += __shfl_xor(zacc, off);
  GATHER_CORE(h)
  float* yr = out + (size_t)w * FD;
  #pragma unroll
  for (int c = 0; c < NC; ++c)
    if ((c & 3) == g || (c == 4 && g == 0)) {
      float4 o = acc[c];
      o.x = o.x / zacc; o.y = o.y / zacc; o.z = o.z / zacc; o.w = o.w / zacc;
      o.x = o.x > 0.f ? o.x : expm1f(o.x);
      o.y = o.y > 0.f ? o.y : expm1f(o.y);
      o.z = o.z > 0.f ? o.z : expm1f(o.z);
      o.w = o.w > 0.f ? o.w : expm1f(o.w);
      *(float4*)(yr + c * 64 + (sub << 2)) = o;
    }
}

// fused level-1 down chunk-0: builds subgraph adjacency + compacted (j, val)
// lists to global (for chunks 1-2) + gathers cols 0..127.
__global__ __launch_bounds__(256) void down1_0k(const int* __restrict__ adjs, const int* __restrict__ degs,
                                                const int* __restrict__ idx, const int* __restrict__ inv,
                                                const float* __restrict__ vals,
                                                const float* __restrict__ Xsrc,
                                                int* __restrict__ adjd, int* __restrict__ degd,
                                                int* __restrict__ ljg, float* __restrict__ lwg,
                                                int* __restrict__ dcomp,
                                                float* __restrict__ Y, int n) {
  constexpr int C0 = 0, NC = 2;
  __shared__ int ljs[4][CAP];
  __shared__ float lws[4][CAP];
  int wv = threadIdx.x >> 6, lane = threadIdx.x & 63;
  int w = blockIdx.x * 4 + wv;
  if (w >= n) return;
  int* lj = ljs[wv]; float* lw = lws[wv];
  int o = idx[w];
  int d0 = degs[o];
  const int* src = adjs + (size_t)o * CAP;
  int* dst = adjd + (size_t)w * CAP;
  int* jg = ljg + (size_t)w * CAP;
  float* wg = lwg + (size_t)w * CAP;
  unsigned long long lm = (1ull << lane) - 1ull;
  int dc = 0;
  for (int t0 = 0; t0 < d0; t0 += 64) {
    int tt = t0 + lane;
    int j = (tt < d0) ? __builtin_nontemporal_load(src + tt) : -1;
    int p = (j >= 0) ? inv[j] : -1;
    unsigned long long mk = __ballot(p >= 0);
    if (p >= 0) {
      int pos = dc + __popcll(mk & lm);
      dst[pos] = p;
      float vv = vals[p];
      lj[pos] = j;
      lw[pos] = vv;
      __builtin_nontemporal_store(j, jg + pos);
      __builtin_nontemporal_store(vv, wg + pos);
    }
    dc += (int)__popcll(mk);
  }
  if (lane < 4) { lj[dc + lane] = 0; lw[dc + lane] = 0.0f; }  // pad for t+g overhang
  if (lane == 0) { degd[w] = dc; dcomp[w] = dc; }
  int d = dc;
  GATHER_CORE(Xsrc)
  float* yr = Y + (size_t)w * FD;
  #pragma unroll
  for (int c = 0; c < NC; ++c)
    if ((c & 3) == g) ntst4(yr + c * 64 + (sub << 2), acc[c]);
}

// masked-unpool chunk-0: compacts (inv-filtered) index list to global + gathers cols 0..127
__global__ __launch_bounds__(256) void msp0_k(const int* __restrict__ adj, const int* __restrict__ deg,
                                              const int* __restrict__ inv,
                                              int* __restrict__ ljg, int* __restrict__ dcomp,
                                              const float* __restrict__ Xp, float* __restrict__ Y, int n) {
  constexpr int C0 = 0, NC = 2;
  __shared__ int ljs[4][CAP];
  __shared__ float lws[4][CAP];
  int wv = threadIdx.x >> 6, lane = threadIdx.x & 63;
  int w = blockIdx.x * 4 + wv;
  if (w >= n) return;
  int* lj = ljs[wv]; float* lw = lws[wv];
  int d0 = deg[w];
  const int* row = adj + (size_t)w * CAP;
  int* jg = ljg + (size_t)w * CAP;
  unsigned long long lm = (1ull << lane) - 1ull;
  int dc = 0;
  for (int t0 = 0; t0 < d0; t0 += 64) {
    int tt = t0 + lane;
    int p = (tt < d0) ? inv[__builtin_nontemporal_load(row + tt)] : -1;
    unsigned long long mk = __ballot(p >= 0);
    if (p >= 0) {
      int pos = dc + __popcll(mk & lm);
      lj[pos] = p;
      lw[pos] = 1.0f;
      __builtin_nontemporal_store(p, jg + pos);
    }
    dc += (int)__popcll(mk);
  }
  if (lane < 4) { lj[dc + lane] = 0; lw[dc + lane] = 0.0f; }
  if (lane == 0) dcomp[w] = dc;
  int d = dc;
  GATHER_CORE(Xp)
  float* yr = Y + (size_t)w * FD;
  #pragma unroll
  for (int c = 0; c < NC; ++c)
    if ((c & 3) == g) ntst4(yr + c * 64 + (sub << 2), acc[c]);
}

// full fused unpool+spmm (single launch) for NN1-sized source (Xb L2-fits)
__global__ __launch_bounds__(256) void mspmm_k(const int* __restrict__ adj, const int* __restrict__ deg,
                                               const int* __restrict__ inv,
                                               const float* __restrict__ Xp, float* __restrict__ Y, int n) {
  constexpr int C0 = 0, NC = 5;
  __shared__ int ljs[4][CAP];
  __shared__ float lws[4][CAP];
  int wv = threadIdx.x >> 6, lane = threadIdx.x & 63;
  int w = blockIdx.x * 4 + wv;
  if (w >= n) return;
  int* lj = ljs[wv]; float* lw = lws[wv];
  int d0 = deg[w];
  const int* row = adj + (size_t)w * CAP;
  unsigned long long lm = (1ull << lane) - 1ull;
  int dc = 0;
  for (int t0 = 0; t0 < d0; t0 += 64) {
    int tt = t0 + lane;
    int p = (tt < d0) ? inv[__builtin_nontemporal_load(row + tt)] : -1;
    unsigned long long mk = __ballot(p >= 0);
    if (p >= 0) {
      int pos = dc + __popcll(mk & lm);
      lj[pos] = p;
      lw[pos] = 1.0f;
    }
    dc += (int)__popcll(mk);
  }
  if (lane < 4) { lj[dc + lane] = 0; lw[dc + lane] = 0.0f; }
  int d = dc;
  GATHER_CORE(Xp)
  float* yr = Y + (size_t)w * FD;
  #pragma unroll
  for (int c = 0; c < NC; ++c)
    if ((c & 3) == g || (c == 4 && g == 0))
      *(float4*)(yr + c * 64 + (sub << 2)) = acc[c];
}

// ---------------- fp32 tiled GEMM with register prefetch (R0, proven) ----------------
__global__ __launch_bounds__(256) void gemm_k(const float* __restrict__ A, const float* __restrict__ A2,
                                              int ksplit,
                                              const int* __restrict__ rowidx, const float* __restrict__ rowscale,
                                              const float* __restrict__ W,
                                              const float* __restrict__ bias, const float* __restrict__ add,
                                              float* __restrict__ C, int n, int K) {
  __shared__ float As[16][68];
  __shared__ float Bs[16][68];
  int t = threadIdx.x;
  int tx = t & 15, ty = t >> 4;
  int row0 = blockIdx.x * 64, col0 = blockIdx.y * 64;
  float acc[4][4] = {};
  int ar = t >> 2;
  int ak = (t & 3) << 2;
  int bk = t >> 4;
  int bc = (t & 15) << 2;
  int grow = row0 + ar;
  int srow = grow;
  float sscale = 1.0f;
  if (grow < n && rowidx) { srow = rowidx[grow]; sscale = rowscale[grow]; }
  auto load_a = [&](int k0) -> float4 {
    float4 av = make_float4(0.f, 0.f, 0.f, 0.f);
    int kk = k0 + ak;
    if (grow < n) {
      const float* src;
      if (A2 && kk >= ksplit) src = A2 + (size_t)srow * (K - ksplit) + (kk - ksplit);
      else                    src = A  + (size_t)srow * (A2 ? ksplit : K) + kk;
      av = *(const float4*)src;
      if (rowidx) { av.x *= sscale; av.y *= sscale; av.z *= sscale; av.w *= sscale; }
    }
    return av;
  };
  float4 av = load_a(0);
  float4 bv = *(const float4*)(W + (size_t)bk * FD + col0 + bc);
  for (int k0 = 0; k0 < K; k0 += 16) {
    As[ak + 0][ar] = av.x; As[ak + 1][ar] = av.y; As[ak + 2][ar] = av.z; As[ak + 3][ar] = av.w;
    *(float4*)&Bs[bk][bc] = bv;
    __syncthreads();
    if (k0 + 16 < K) {
      av = load_a(k0 + 16);
      bv = *(const float4*)(W + (size_t)(k0 + 16 + bk) * FD + col0 + bc);
    }
#pragma unroll
    for (int kkk = 0; kkk < 16; ++kkk) {
      float af[4], bf[4];
      *(float4*)af = *(const float4*)&As[kkk][ty << 2];
      *(float4*)bf = *(const float4*)&Bs[kkk][tx << 2];
#pragma unroll
      for (int i = 0; i < 4; ++i)
#pragma unroll
        for (int j = 0; j < 4; ++j) acc[i][j] = fmaf(af[i], bf[j], acc[i][j]);
    }
    __syncthreads();
  }
#pragma unroll
  for (int i = 0; i < 4; ++i) {
    int r = row0 + (ty << 2) + i;
    if (r >= n) continue;
    int c = col0 + (tx << 2);
    float4 v;
    v.x = acc[i][0]; v.y = acc[i][1]; v.z = acc[i][2]; v.w = acc[i][3];
    if (bias) { v.x += bias[c]; v.y += bias[c + 1]; v.z += bias[c + 2]; v.w += bias[c + 3]; }
    if (add) {
      const float* ad = add + (size_t)r * FD + c;
      v.x += ad[0]; v.y += ad[1]; v.z += ad[2]; v.w += ad[3];
    }
    *(float4*)(C + (size_t)r * FD + c) = v;
  }
}

static inline unsigned cdiv(int a, int b) { return (unsigned)((a + b - 1) / b); }

static void launch_gemm(const float* A, const float* W, const float* bias, const float* add,
                        float* C, int n, int K, hipStream_t stream, const float* A2 = nullptr,
                        int ksplit = 0, const int* rowidx = nullptr, const float* rowscale = nullptr) {
  gemm_k<<<dim3(cdiv(n, 64), 5), dim3(256), 0, stream>>>(A, A2, ksplit, rowidx, rowscale,
                                                         W, bias, add, C, n, K);
}

// ---------------- GAT helpers ----------------
__global__ __launch_bounds__(256) void esed_k(const float* __restrict__ h, const float* __restrict__ a,
                                              float* __restrict__ es, float* __restrict__ ed, int n) {
  int w = blockIdx.x * 4 + (threadIdx.x >> 6);
  int lane = threadIdx.x & 63;
  if (w >= n) return;
  const float* hr = h + (size_t)w * FD;
  const float* a2 = a + FD;
  float sa = 0.f, sb = 0.f;
#pragma unroll
  for (int c = 0; c < 5; ++c) {
    float hv = hr[lane + 64 * c];
    sa += hv * a[lane + 64 * c];
    sb += hv * a2[lane + 64 * c];
  }
  for (int o = 32; o; o >>= 1) { sa += __shfl_xor(sa, o); sb += __shfl_xor(sb, o); }
  if (lane == 0) { es[w] = sa; ed[w] = sb; }
}

// ---------------- pooling: fused score + key build + rank zero ----------------
__global__ __launch_bounds__(256) void scorekey_k(const float* __restrict__ X, const float* __restrict__ pw,
                                                  const float* __restrict__ pb,
                                                  unsigned long long* __restrict__ keys,
                                                  int* __restrict__ rank, int n) {
  int w = blockIdx.x * 4 + (threadIdx.x >> 6);
  int lane = threadIdx.x & 63;
  if (w >= n) return;
  const float* xr = X + (size_t)w * FD;
  float s = 0.f;
#pragma unroll
  for (int c = 0; c < 5; ++c) s += xr[lane + 64 * c] * pw[lane + 64 * c];
  for (int o = 32; o; o >>= 1) s += __shfl_xor(s, o);
  if (lane == 0) {
    float u = (s + pb[0]) / 100.0f;
    float sc = 1.0f / (1.0f + expf(-u));
    keys[w] = ((unsigned long long)__float_as_uint(sc) << 32) | (unsigned int)(~w);
    rank[w] = 0;
  }
}

#define RANK_TILE 1024
__global__ __launch_bounds__(256) void rank_count_k(const unsigned long long* __restrict__ keys,
                                                    int n, int jchunk, int* __restrict__ rank) {
  __shared__ unsigned long long tile[RANK_TILE];
  int i = blockIdx.x * 256 + threadIdx.x;
  unsigned long long my = (i < n) ? keys[i] : 0ull;
  int j0 = blockIdx.y * jchunk;
  int jend = j0 + jchunk; if (jend > n) jend = n;
  int cnt = 0;
  for (int t0 = j0; t0 < jend; t0 += RANK_TILE) {
    int m = jend - t0; if (m > RANK_TILE) m = RANK_TILE;
    for (int t = threadIdx.x; t < m; t += 256) tile[t] = keys[t0 + t];
    __syncthreads();
    for (int t = 0; t < m; ++t) cnt += (tile[t] > my) ? 1 : 0;
    __syncthreads();
  }
  if (i < n && cnt) atomicAdd(&rank[i], cnt);
}

__global__ __launch_bounds__(256) void rank_scatter_k(const unsigned long long* __restrict__ keys,
                                                      const int* __restrict__ rank, int n, int k,
                                                      int* __restrict__ idx_out, float* __restrict__ vals_out,
                                                      int* __restrict__ inv) {
  int i = blockIdx.x * 256 + threadIdx.x;
  if (i >= n) return;
  int r = rank[i];
  inv[i] = (r < k) ? r : -1;
  if (r < k) {
    idx_out[r] = i;
    vals_out[r] = __uint_as_float((unsigned int)(keys[i] >> 32));
  }
}

// ---------------- host ----------------
static inline dim3 wgrid(int n) { return dim3((unsigned)((n + 3) / 4)); }

struct TopkBufs { unsigned long long* keys; int* rank; };

static void launch_topk(int n, int k, int* idx_out, float* vals_out, int* inv,
                        TopkBufs tb, hipStream_t stream) {
  const int JS = 8;
  int jchunk = (n + JS - 1) / JS;
  rank_count_k<<<dim3(cdiv(n, 256), JS), dim3(256), 0, stream>>>(tb.keys, n, jchunk, tb.rank);
  rank_scatter_k<<<cdiv(n, 256), dim3(256), 0, stream>>>(tb.keys, tb.rank, n, k, idx_out, vals_out, inv);
}

extern "C" void kernel_launch(void* const* d_in, const int* in_sizes, int n_in,
                              void* d_out, int out_size, void* d_ws, size_t ws_size,
                              hipStream_t stream) {
  const float* A      = (const float*)d_in[0];
  const float* X0     = (const float*)d_in[1];
  const float* sg_W   = (const float*)d_in[2];
  const float* sg_a   = (const float*)d_in[3];
  const float* bg_W   = (const float*)d_in[4];
  const float* bg_a   = (const float*)d_in[5];
  const float* eg_W   = (const float*)d_in[6];
  const float* eg_a   = (const float*)d_in[7];
  const float* down_W = (const float*)d_in[8];
  const float* down_b = (const float*)d_in[9];
  const float* up_W   = (const float*)d_in[10];
  const float* up_b   = (const float*)d_in[11];
  const float* pool_w = (const float*)d_in[12];
  const float* pool_b = (const float*)d_in[13];
  float* out = (float*)d_out;
  char* ws = (char*)d_ws;

  size_t off = 0;
  auto alloc = [&](size_t bytes) -> char* {
    char* p = ws + off;
    off += (bytes + 255) & ~(size_t)255;
    return p;
  };
  int* adj0  = (int*)alloc((size_t)N0 * CAP * 4);
  int* deg0  = (int*)alloc((size_t)N0 * 4);
  int* adj1a = (int*)alloc((size_t)NN1 * CAP * 4);
  int* deg1a = (int*)alloc((size_t)NN1 * 4);
  int* adj1b = (int*)alloc((size_t)NN1 * CAP * 4);
  int* deg1b = (int*)alloc((size_t)NN1 * 4);
  int* adj2  = (int*)alloc((size_t)NN2 * CAP * 4);
  int* deg2  = (int*)alloc((size_t)NN2 * 4);
  int* inv0a = (int*)alloc((size_t)N0 * 4);
  int* inv0b = (int*)alloc((size_t)N0 * 4);
  int* inv1a = (int*)alloc((size_t)NN1 * 4);
  int* inv1b = (int*)alloc((size_t)NN1 * 4);
  int* idx0a = (int*)alloc((size_t)NN1 * 4);
  int* idx0b = (int*)alloc((size_t)NN1 * 4);
  int* idx1a = (int*)alloc((size_t)NN2 * 4);
  int* idx1b = (int*)alloc((size_t)NN2 * 4);
  unsigned long long* keys = (unsigned long long*)alloc((size_t)N0 * 8);
  int* rankb = (int*)alloc((size_t)N0 * 4);
  float* vals   = (float*)alloc((size_t)N0 * 4);
  float* es     = (float*)alloc((size_t)N0 * 4);
  float* ed     = (float*)alloc((size_t)N0 * 4);
  float* hbuf   = (float*)alloc((size_t)N0 * FD * 4);
  float* S      = (float*)alloc((size_t)N0 * FD * 4);
  float* Xcur   = (float*)alloc((size_t)N0 * FD * 4);
  float* d0a    = (float*)alloc((size_t)N0 * FD * 4);
  float* d1a    = (float*)alloc((size_t)NN1 * FD * 4);
  float* d0b    = (float*)alloc((size_t)N0 * FD * 4);
  float* d1b    = (float*)alloc((size_t)NN1 * FD * 4);
  float* Xb     = (float*)alloc((size_t)NN2 * FD * 4);
  float* Xu1    = (float*)alloc((size_t)NN1 * FD * 4);
  float* Xu0    = (float*)alloc((size_t)N0 * FD * 4);
  // chunked-gather spill buffers
  int*   wbufJ  = (int*)alloc((size_t)N0 * CAP * 4);
  float* wbufW  = (float*)alloc((size_t)N0 * CAP * 4);
  int*   dcomp  = (int*)alloc((size_t)N0 * 4);
  float* zbuf   = (float*)alloc((size_t)N0 * 4);

  TopkBufs tb{keys, rankb};
  dim3 b256(256);

  build_adj_k<<<wgrid(N0), b256, 0, stream>>>(A, adj0, deg0);

  float* orgX = out + (size_t)N0 * FD;   // "start" output, also org_X
  launch_gemm(X0, sg_W, nullptr, nullptr, hbuf, N0, FD, stream);
  esed_k<<<wgrid(N0), b256, 0, stream>>>(hbuf, sg_a, es, ed, N0);
  gat0_k<<<wgrid(N0), b256, 0, stream>>>(adj0, deg0, hbuf, es, ed, wbufW, zbuf, orgX, N0);
  gatherw_k<2, 2, true><<<wgrid(N0), b256, 0, stream>>>(adj0, deg0, nullptr, wbufW, nullptr, hbuf, zbuf, orgX, N0);
  gatherw_k<4, 1, true><<<wgrid(N0), b256, 0, stream>>>(adj0, deg0, nullptr, wbufW, nullptr, hbuf, zbuf, orgX, N0);

  const float* Xin = orgX;
  for (int pass = 0; pass < 2; ++pass) {
    int* idx0p = pass ? idx0b : idx0a;
    int* inv0p = pass ? inv0b : inv0a;
    int* idx1p = pass ? idx1b : idx1a;
    int* inv1p = pass ? inv1b : inv1a;
    int* adj1p = pass ? adj1b : adj1a;
    int* deg1p = pass ? deg1b : deg1a;
    float* d0p = pass ? d0b : d0a;
    float* d1p = pass ? d1b : d1a;

    // ---- down level 0 (n = N0): plain spmm, 3 column chunks ----
    gatherw_k<0, 2, false><<<wgrid(N0), b256, 0, stream>>>(adj0, deg0, nullptr, nullptr, nullptr, Xin, nullptr, S, N0);
    gatherw_k<2, 2, false><<<wgrid(N0), b256, 0, stream>>>(adj0, deg0, nullptr, nullptr, nullptr, Xin, nullptr, S, N0);
    gatherw_k<4, 1, false><<<wgrid(N0), b256, 0, stream>>>(adj0, deg0, nullptr, nullptr, nullptr, Xin, nullptr, S, N0);
    launch_gemm(S, down_W, down_b, nullptr, d0p, N0, FD, stream);
    scorekey_k<<<wgrid(N0), b256, 0, stream>>>(d0p, pool_w, pool_b, keys, rankb, N0);
    launch_topk(N0, NN1, idx0p, vals, inv0p, tb, stream);

    // ---- down level 1 (n = NN1): chunk0 builds adj + compaction, chunks 1-2 pure ----
    down1_0k<<<wgrid(NN1), b256, 0, stream>>>(adj0, deg0, idx0p, inv0p, vals, d0p,
                                              adj1p, deg1p, wbufJ, wbufW, dcomp, S, NN1);
    gatherw_k<2, 2, false><<<wgrid(NN1), b256, 0, stream>>>(nullptr, nullptr, wbufJ, wbufW, dcomp, d0p, nullptr, S, NN1);
    gatherw_k<4, 1, false><<<wgrid(NN1), b256, 0, stream>>>(nullptr, nullptr, wbufJ, wbufW, dcomp, d0p, nullptr, S, NN1);
    launch_gemm(S, down_W + FD * FD, down_b + FD, nullptr, d1p, NN1, FD, stream);
    scorekey_k<<<wgrid(NN1), b256, 0, stream>>>(d1p, pool_w + FD, pool_b + 1, keys, rankb, NN1);
    launch_topk(NN1, NN2, idx1p, vals, inv1p, tb, stream);
    sub_adj_k<<<wgrid(NN2), b256, 0, stream>>>(adj1p, deg1p, idx1p, inv1p, adj2, deg2, NN2);

    // ---- bottom GAT (n = NN2): source L2-fits, single launch ----
    launch_gemm(d1p, bg_W, nullptr, nullptr, hbuf, NN2, FD, stream, nullptr, 0, idx1p, vals);
    esed_k<<<wgrid(NN2), b256, 0, stream>>>(hbuf, bg_a, es, ed, NN2);
    gat_k<<<wgrid(NN2), b256, 0, stream>>>(adj2, deg2, hbuf, es, ed, Xb, NN2);

    // ---- up path: ALWAYS pass-1 ("a") graph state, per reference indexing ----
    mspmm_k<<<wgrid(NN1), b256, 0, stream>>>(adj1a, deg1a, inv1a, Xb, S, NN1);
    launch_gemm(S, up_W, up_b, d1a, Xu1, NN1, FD, stream);
    msp0_k<<<wgrid(N0), b256, 0, stream>>>(adj0, deg0, inv0a, wbufJ, dcomp, Xu1, S, N0);
    gatherw_k<2, 2, false><<<wgrid(N0), b256, 0, stream>>>(nullptr, nullptr, wbufJ, nullptr, dcomp, Xu1, nullptr, S, N0);
    gatherw_k<4, 1, false><<<wgrid(N0), b256, 0, stream>>>(nullptr, nullptr, wbufJ, nullptr, dcomp, Xu1, nullptr, S, N0);
    launch_gemm(S, up_W + FD * FD, up_b + FD, d0a, Xu0, N0, FD, stream);

    // ---- end GAT on concat([Xu0, org_X]) fused into the GEMM A-loader ----
    launch_gemm(Xu0, eg_W, nullptr, nullptr, hbuf, N0, 2 * FD, stream, orgX, FD);
    esed_k<<<wgrid(N0), b256, 0, stream>>>(hbuf, eg_a, es, ed, N0);
    float* egout = pass ? out : Xcur;
    gat0_k<<<wgrid(N0), b256, 0, stream>>>(adj0, deg0, hbuf, es, ed, wbufW, zbuf, egout, N0);
    gatherw_k<2, 2, true><<<wgrid(N0), b256, 0, stream>>>(adj0, deg0, nullptr, wbufW, nullptr, hbuf, zbuf, egout, N0);
    gatherw_k<4, 1, true><<<wgrid(N0), b256, 0, stream>>>(adj0, deg0, nullptr, wbufW, nullptr, hbuf, zbuf, egout, N0);
    Xin = egout;
  }
}